// Round 1
// baseline (607.033 us; speedup 1.0000x reference)
//
#include <hip/hip_runtime.h>
#include <math.h>

#define LI 2048
#define LT 384
#define LSEQ 2432
#define DM 2560
#define NH 20
#define DH 128
#define NT_K 40
#define SCALE 0.08838834764831845f

typedef __bf16 bf16x8 __attribute__((ext_vector_type(8)));
typedef __bf16 bf16x4 __attribute__((ext_vector_type(4)));
typedef __bf16 bf16x2 __attribute__((ext_vector_type(2)));
typedef float f32x4 __attribute__((ext_vector_type(4)));

__device__ __forceinline__ void async_copy16(const void* gsrc, void* lds_uniform) {
    __builtin_amdgcn_global_load_lds(
        (const __attribute__((address_space(1))) unsigned int*)gsrc,
        (__attribute__((address_space(3))) unsigned int*)lds_uniform,
        16, 0, 0);
}

#define SBAR()  __builtin_amdgcn_s_barrier()
#define LGKM0() asm volatile("s_waitcnt lgkmcnt(0)" ::: "memory")
#define CFENCE() asm volatile("" ::: "memory")

// ---------------- f32 -> bf16 conversions ----------------

__global__ __launch_bounds__(256) void cvt8_kernel(
    const float* __restrict__ s0, const float* __restrict__ s1,
    const float* __restrict__ s2, const float* __restrict__ s3,
    const float* __restrict__ s4, const float* __restrict__ s5,
    const float* __restrict__ s6, const float* __restrict__ s7,
    __bf16* __restrict__ dst)
{
    const float* srcs[8] = {s0, s1, s2, s3, s4, s5, s6, s7};
    const float* s = srcs[blockIdx.y];
    __bf16* d = dst + (size_t)blockIdx.y * (size_t)DM * DM;
    int i = blockIdx.x * 256 + threadIdx.x;
    const float4* sp = (const float4*)s + (size_t)i * 2;
    float4 a = sp[0], b = sp[1];
    bf16x8 o = {(__bf16)a.x, (__bf16)a.y, (__bf16)a.z, (__bf16)a.w,
                (__bf16)b.x, (__bf16)b.y, (__bf16)b.z, (__bf16)b.w};
    *((bf16x8*)d + i) = o;
}

__global__ __launch_bounds__(256) void cvt_kernel(
    const float* __restrict__ s, __bf16* __restrict__ d, int n8)
{
    int i = blockIdx.x * 256 + threadIdx.x;
    if (i >= n8) return;
    const float4* sp = (const float4*)s + (size_t)i * 2;
    float4 a = sp[0], b = sp[1];
    bf16x8 o = {(__bf16)a.x, (__bf16)a.y, (__bf16)a.z, (__bf16)a.w,
                (__bf16)b.x, (__bf16)b.y, (__bf16)b.z, (__bf16)b.w};
    *((bf16x8*)d + i) = o;
}

// ---------------- 128x128 bf16 GEMM core (2-phase) — kept for out-proj ----------------

__device__ __forceinline__ void gemm_core(
    const __bf16* __restrict__ Ab,
    const __bf16* __restrict__ Bb,
    const float* __restrict__ bias,
    float* __restrict__ Cb,
    __bf16* sA, __bf16* sB)
{
    const int t = threadIdx.x, wave = t >> 6, lane = t & 63;
    const int l15 = lane & 15, quad = lane >> 4;
    const int wm = wave >> 1, wn = wave & 1;

    f32x4 acc[4][4];
#pragma unroll
    for (int i = 0; i < 4; i++)
#pragma unroll
        for (int j = 0; j < 4; j++) acc[i][j] = f32x4{0.f, 0.f, 0.f, 0.f};

    size_t soff[4];
#pragma unroll
    for (int j = 0; j < 4; j++) {
        int c = j * 256 + t;
        int row = c >> 3, u = c & 7;
        soff[j] = (size_t)row * DM + ((u ^ (row & 7)) * 8);
    }

    for (int k0 = 0; k0 < DM; k0 += 64) {
        __syncthreads();
#pragma unroll
        for (int j = 0; j < 4; j++)
            async_copy16(Ab + soff[j] + k0, (char*)sA + (j * 256 + wave * 64) * 16);
#pragma unroll
        for (int j = 0; j < 4; j++)
            async_copy16(Bb + soff[j] + k0, (char*)sB + (j * 256 + wave * 64) * 16);
        __syncthreads();

#pragma unroll
        for (int ks = 0; ks < 2; ks++) {
            bf16x8 af[4], bg[4];
#pragma unroll
            for (int mt = 0; mt < 4; mt++) {
                int r = wm * 64 + mt * 16 + l15;
                af[mt] = *(const bf16x8*)(sA + r * 64 + (((quad + ks * 4) ^ (r & 7)) * 8));
            }
#pragma unroll
            for (int nt = 0; nt < 4; nt++) {
                int r = wn * 64 + nt * 16 + l15;
                bg[nt] = *(const bf16x8*)(sB + r * 64 + (((quad + ks * 4) ^ (r & 7)) * 8));
            }
#pragma unroll
            for (int mt = 0; mt < 4; mt++)
#pragma unroll
                for (int nt = 0; nt < 4; nt++)
                    acc[mt][nt] = __builtin_amdgcn_mfma_f32_16x16x32_bf16(af[mt], bg[nt], acc[mt][nt], 0, 0, 0);
        }
    }

#pragma unroll
    for (int mt = 0; mt < 4; mt++) {
        const int row = wm * 64 + mt * 16 + quad * 4;
#pragma unroll
        for (int nt = 0; nt < 4; nt++) {
            const int col = wn * 64 + nt * 16 + l15;
            const float bv = bias[col];
            float* cp = Cb + (size_t)row * DM + col;
            cp[0]        = acc[mt][nt][0] + bv;
            cp[DM]       = acc[mt][nt][1] + bv;
            cp[2 * DM]   = acc[mt][nt][2] + bv;
            cp[3 * DM]   = acc[mt][nt][3] + bv;
        }
    }
}

// Out-proj: grid (20, 19). 380 blocks spread better than 100x256^2 blocks would.
__global__ __launch_bounds__(256, 4) void gemm_out_kernel(
    const __bf16* __restrict__ attnbf, const __bf16* __restrict__ wbf,
    const float* __restrict__ bo, const float* __restrict__ bo_t,
    float* __restrict__ out)
{
    __shared__ alignas(16) __bf16 sA[128 * 64];
    __shared__ alignas(16) __bf16 sB[128 * 64];
    const int nblk = blockIdx.x, mblk = blockIdx.y;
    const bool is_txt = (mblk >= 16);
    const size_t WELEM = (size_t)DM * DM;
    const __bf16* W = wbf + (size_t)(is_txt ? 7 : 3) * WELEM;
    const float* bias = (is_txt ? bo_t : bo) + nblk * 128;
    gemm_core(attnbf + (size_t)mblk * 128 * DM, W + (size_t)nblk * 128 * DM, bias,
              out + (size_t)mblk * 128 * DM + nblk * 128, sA, sB);
}

// ---------------- 256x256 8-phase BK=64 counted-vmcnt GEMM (T2+T3+T4+T5) ----------------
// 512 threads = 8 waves (2M x 4N); per-wave 128x64 output; acc[8][4] f32x4.
// LDS 128 KiB = 2 dbuf x (A 256x64 + B 256x64) bf16, same XOR-unit swizzle as gemm_core.
// Per K-tile tau: 4 phases = quadrants (mh,nh), 16 MFMA each.
//   B-LDS dead after P2 -> stage B(tau+2) at P3; A-LDS dead after P3 -> stage A(tau+2) at P4.
//   Per-tile drain: s_waitcnt vmcnt(8) (keeps tau+2's 8 loads/thread in flight) + s_barrier.

__device__ __forceinline__ void stage_half2(
    const __bf16* panel, char* dst, int k0, size_t soff0, size_t soff1)
{
    // stages a full 256x64 tile of one matrix: 4 x 16B per thread (2 per 128-row half)
    async_copy16(panel + soff0 + k0, dst);
    async_copy16(panel + soff1 + k0, dst + 8192);
    async_copy16(panel + (size_t)128 * DM + soff0 + k0, dst + 16384);
    async_copy16(panel + (size_t)128 * DM + soff1 + k0, dst + 16384 + 8192);
}

__device__ __forceinline__ void gemm8_core(
    const __bf16* __restrict__ Ap,   // 256 rows, ld=DM
    const __bf16* __restrict__ Bp,   // 256 n-rows, ld=DM
    const float* __restrict__ bias,  // 256
    float* __restrict__ Cb,          // 256x256 at ld=DM
    __bf16* sA, __bf16* sB)
{
    const int t = threadIdx.x;
    const int wave = t >> 6, lane = t & 63;
    const int l15 = lane & 15, quad = lane >> 4;
    const int wm = wave >> 2, wn = wave & 3;
    const int sw = l15 & 7;

    // staging source offsets (swizzle pre-inverted); c = j*512 + t, row = c>>3 in a 128-row half
    const int srow = t >> 3;
    const size_t soff0 = (size_t)srow * DM + (((t & 7) ^ (srow & 7)) * 8);
    const size_t soff1 = soff0 + (size_t)64 * DM;   // j=1: rows 64..127 of the half

    char* const dA = (char*)sA + wave * 1024;       // HW adds lane*16
    char* const dB = (char*)sB + wave * 1024;

    f32x4 acc[8][4];
#pragma unroll
    for (int i = 0; i < 8; i++)
#pragma unroll
        for (int j = 0; j < 4; j++) acc[i][j] = f32x4{0.f, 0.f, 0.f, 0.f};

    // prologue: tile0 -> buf0, tile1 -> buf1 (tile0's 8 loads strictly precede tile1's)
    stage_half2(Ap, dA, 0, soff0, soff1);
    stage_half2(Bp, dB, 0, soff0, soff1);
    CFENCE();
    stage_half2(Ap, dA + 32768, 64, soff0, soff1);
    stage_half2(Bp, dB + 32768, 64, soff0, soff1);
    asm volatile("s_waitcnt vmcnt(8)" ::: "memory");   // tile0 landed (each wave's share)
    SBAR();                                            // -> whole tile0 in LDS

    for (int tau = 0; tau < NT_K; ++tau) {
        const __bf16* bA = sA + ((tau & 1) << 14);
        const __bf16* bB = sB + ((tau & 1) << 14);
        char* dAc = dA + ((tau & 1) << 15);            // tile tau+2 shares parity with tau
        char* dBc = dB + ((tau & 1) << 15);
        const int kpf = tau * 64 + 128;
        const bool pf = (kpf < DM);

        const __bf16* rA = bA + (size_t)(wm * 128 + l15) * 64;
        const __bf16* rB = bB + (size_t)(wn * 64 + l15) * 64;

        bf16x8 a0[4][2], b0[2][2], b1[2][2];

        // ---- P1: read A(mh0) + B(nh0); MFMA quadrant (0,0)
#pragma unroll
        for (int mt = 0; mt < 4; mt++)
#pragma unroll
            for (int ks = 0; ks < 2; ks++)
                a0[mt][ks] = *(const bf16x8*)(rA + mt * (16 * 64) + (((ks * 4 + quad) ^ sw) * 8));
#pragma unroll
        for (int nt = 0; nt < 2; nt++)
#pragma unroll
            for (int ks = 0; ks < 2; ks++)
                b0[nt][ks] = *(const bf16x8*)(rB + nt * (16 * 64) + (((ks * 4 + quad) ^ sw) * 8));
        SBAR(); LGKM0();
        __builtin_amdgcn_s_setprio(1);
#pragma unroll
        for (int ks = 0; ks < 2; ks++)
#pragma unroll
            for (int mt = 0; mt < 4; mt++)
#pragma unroll
                for (int nt = 0; nt < 2; nt++)
                    acc[mt][nt] = __builtin_amdgcn_mfma_f32_16x16x32_bf16(a0[mt][ks], b0[nt][ks], acc[mt][nt], 0, 0, 0);
        __builtin_amdgcn_s_setprio(0);
        SBAR();

        // ---- P2: read B(nh1); MFMA (0,1)
#pragma unroll
        for (int nt = 0; nt < 2; nt++)
#pragma unroll
            for (int ks = 0; ks < 2; ks++)
                b1[nt][ks] = *(const bf16x8*)(rB + (nt + 2) * (16 * 64) + (((ks * 4 + quad) ^ sw) * 8));
        SBAR(); LGKM0();
        __builtin_amdgcn_s_setprio(1);
#pragma unroll
        for (int ks = 0; ks < 2; ks++)
#pragma unroll
            for (int mt = 0; mt < 4; mt++)
#pragma unroll
                for (int nt = 0; nt < 2; nt++)
                    acc[mt][nt + 2] = __builtin_amdgcn_mfma_f32_16x16x32_bf16(a0[mt][ks], b1[nt][ks], acc[mt][nt + 2], 0, 0, 0);
        __builtin_amdgcn_s_setprio(0);
        SBAR();

        // ---- P3: read A(mh1); stage B(tau+2) (B-LDS reads all drained at P2); MFMA (1,0)
#pragma unroll
        for (int mt = 0; mt < 4; mt++)
#pragma unroll
            for (int ks = 0; ks < 2; ks++)
                a0[mt][ks] = *(const bf16x8*)(rA + (mt + 4) * (16 * 64) + (((ks * 4 + quad) ^ sw) * 8));
        if (pf) stage_half2(Bp, dBc, kpf, soff0, soff1);
        SBAR(); LGKM0();
        __builtin_amdgcn_s_setprio(1);
#pragma unroll
        for (int ks = 0; ks < 2; ks++)
#pragma unroll
            for (int mt = 0; mt < 4; mt++)
#pragma unroll
                for (int nt = 0; nt < 2; nt++)
                    acc[mt + 4][nt] = __builtin_amdgcn_mfma_f32_16x16x32_bf16(a0[mt][ks], b0[nt][ks], acc[mt + 4][nt], 0, 0, 0);
        __builtin_amdgcn_s_setprio(0);
        SBAR();

        // ---- P4: stage A(tau+2) (A-LDS reads drained at P3); MFMA (1,1); tile drain
        if (pf) stage_half2(Ap, dAc, kpf, soff0, soff1);
        SBAR();
        __builtin_amdgcn_s_setprio(1);
#pragma unroll
        for (int ks = 0; ks < 2; ks++)
#pragma unroll
            for (int mt = 0; mt < 4; mt++)
#pragma unroll
                for (int nt = 0; nt < 2; nt++)
                    acc[mt + 4][nt + 2] = __builtin_amdgcn_mfma_f32_16x16x32_bf16(a0[mt][ks], b1[nt][ks], acc[mt + 4][nt + 2], 0, 0, 0);
        __builtin_amdgcn_s_setprio(0);
        // drain tile tau+1 (keep tau+2's 8 loads in flight); last prefetched tile needs full drain
        if (tau == NT_K - 2) { asm volatile("s_waitcnt vmcnt(0)" ::: "memory"); }
        else                 { asm volatile("s_waitcnt vmcnt(8)" ::: "memory"); }
        SBAR();
    }

    float bvl[4];
#pragma unroll
    for (int nt = 0; nt < 4; nt++) bvl[nt] = bias[wn * 64 + nt * 16 + l15];
#pragma unroll
    for (int mt = 0; mt < 8; mt++) {
        const int row = wm * 128 + mt * 16 + quad * 4;
#pragma unroll
        for (int nt = 0; nt < 4; nt++) {
            float* cp = Cb + (size_t)row * DM + wn * 64 + nt * 16 + l15;
            cp[0]      = acc[mt][nt][0] + bvl[nt];
            cp[DM]     = acc[mt][nt][1] + bvl[nt];
            cp[2 * DM] = acc[mt][nt][2] + bvl[nt];
            cp[3 * DM] = acc[mt][nt][3] + bvl[nt];
        }
    }
}

// QKV: grid (30, 10) — x = which*10 + ntile, y = mtile (256 rows; tile 9 overlaps to cover 2432).
// img/txt weight split at row 2048 = tile 8 boundary; tiles 8,9 are both txt.
__global__ __launch_bounds__(512, 2) void gemm8_qkv_kernel(
    const __bf16* __restrict__ xbf, const __bf16* __restrict__ wbf,
    const float* __restrict__ bq, const float* __restrict__ bk, const float* __restrict__ bv,
    const float* __restrict__ bq_t, const float* __restrict__ bk_t, const float* __restrict__ bv_t,
    float* __restrict__ qraw, float* __restrict__ kraw, float* __restrict__ vraw)
{
    extern __shared__ __align__(16) char dynsmem[];   // 131072 B
    __bf16* sA = (__bf16*)dynsmem;
    __bf16* sB = (__bf16*)(dynsmem + 65536);

    const int nblk = blockIdx.x, mblk = blockIdx.y;
    const int which = nblk / 10;                 // 0=Q 1=K 2=V
    const int nloc = (nblk % 10) * 256;
    const int mstart = (mblk < 9) ? (mblk * 256) : (LSEQ - 256);   // overlap tile covers tail
    const bool is_txt = (mblk >= 8);
    const size_t WELEM = (size_t)DM * DM;
    const int widx = which + (is_txt ? 4 : 0);
    const __bf16* W = wbf + (size_t)widx * WELEM;
    const float* bias = (which == 0) ? (is_txt ? bq_t : bq)
                      : (which == 1) ? (is_txt ? bk_t : bk)
                                     : (is_txt ? bv_t : bv);
    float* C = (which == 0) ? qraw : (which == 1) ? kraw : vraw;
    gemm8_core(xbf + (size_t)mstart * DM, W + (size_t)nloc * DM, bias + nloc,
               C + (size_t)mstart * DM + nloc, sA, sB);
}

// ---------------- RMS norm + qn/kn + mask + RoPE, f32 -> bf16 ----------------

__global__ __launch_bounds__(256) void rmsrope_kernel(
    const float* __restrict__ qraw, const float* __restrict__ kraw,
    const float* __restrict__ rope, const float* __restrict__ img_masks,
    const float* __restrict__ qn, const float* __restrict__ kn,
    const float* __restrict__ qn_t, const float* __restrict__ kn_t,
    __bf16* __restrict__ qbf, __bf16* __restrict__ kbf)
{
    const int l = blockIdx.x, t = threadIdx.x;
    const int wave = t >> 6, lane = t & 63;
    const bool is_img = (l < LI);
    const float* qw = is_img ? qn : qn_t;
    const float* kw = is_img ? kn : kn_t;
    const float kmask = is_img ? img_masks[l] : 1.0f;
    const float* qr = qraw + (size_t)l * DM;
    const float* kr = kraw + (size_t)l * DM;

    float2 qv[5], kv[5];
    float sq = 0.f, sk = 0.f;
#pragma unroll
    for (int j = 0; j < 5; j++) {
        int c2 = j * 256 + t;
        qv[j] = *(const float2*)(qr + 2 * c2);
        kv[j] = *(const float2*)(kr + 2 * c2);
        sq += qv[j].x * qv[j].x + qv[j].y * qv[j].y;
        sk += kv[j].x * kv[j].x + kv[j].y * kv[j].y;
    }
#pragma unroll
    for (int m = 32; m; m >>= 1) { sq += __shfl_xor(sq, m); sk += __shfl_xor(sk, m); }
    __shared__ float redq[4], redk[4];
    if (lane == 0) { redq[wave] = sq; redk[wave] = sk; }
    __syncthreads();
    sq = redq[0] + redq[1] + redq[2] + redq[3];
    sk = redk[0] + redk[1] + redk[2] + redk[3];
    const float rq = rsqrtf(sq * (1.0f / DM) + 1e-5f);
    const float rk = rsqrtf(sk * (1.0f / DM) + 1e-5f) * kmask;

#pragma unroll
    for (int j = 0; j < 5; j++) {
        int c2 = j * 256 + t;
        int c = 2 * c2;
        float4 rp = *(const float4*)(rope + ((size_t)l * 64 + (c2 & 63)) * 4);
        float2 w2q = *(const float2*)(qw + c);
        float2 w2k = *(const float2*)(kw + c);
        float x0 = qv[j].x * rq * w2q.x, x1 = qv[j].y * rq * w2q.y;
        bf16x2 oq = {(__bf16)(rp.x * x0 + rp.y * x1), (__bf16)(rp.z * x0 + rp.w * x1)};
        *(bf16x2*)(qbf + (size_t)l * DM + c) = oq;
        float y0 = kv[j].x * rk * w2k.x, y1 = kv[j].y * rk * w2k.y;
        bf16x2 ok = {(__bf16)(rp.x * y0 + rp.y * y1), (__bf16)(rp.z * y0 + rp.w * y1)};
        *(bf16x2*)(kbf + (size_t)l * DM + c) = ok;
    }
}

// ---------------- transpose V (L,DM) f32 -> (DM,L) bf16 ----------------

__global__ __launch_bounds__(256) void transpose_cvt_kernel(
    const float* __restrict__ src, __bf16* __restrict__ dst)
{
    __shared__ float tile[32][33];
    const int c0 = blockIdx.x * 32;
    const int r0 = blockIdx.y * 32;
    const int tc = threadIdx.x & 31, tr = threadIdx.x >> 5;
#pragma unroll
    for (int j = 0; j < 4; j++)
        tile[tr + j * 8][tc] = src[(size_t)(r0 + tr + j * 8) * DM + c0 + tc];
    __syncthreads();
#pragma unroll
    for (int j = 0; j < 4; j++)
        dst[(size_t)(c0 + tr + j * 8) * LSEQ + r0 + tc] = (__bf16)tile[tc][tr + j * 8];
}

// ---------------- flash attention ----------------

__global__ __launch_bounds__(256, 4) void flash_kernel(
    const __bf16* __restrict__ qb, const __bf16* __restrict__ kb,
    const __bf16* __restrict__ vt, __bf16* __restrict__ ob)
{
    __shared__ alignas(16) __bf16 sK[64 * DH];
    __shared__ alignas(16) __bf16 sV[DH * 64];
    __shared__ alignas(16) __bf16 sP[4 * 16 * 64];
    const int head = blockIdx.x;
    const int q0 = blockIdx.y * 64;
    const int t = threadIdx.x, wave = t >> 6, lane = t & 63;
    const int l15 = lane & 15, quad = lane >> 4;
    const int qrow = q0 + wave * 16 + l15;

    bf16x8 aq[4];
#pragma unroll
    for (int d = 0; d < 4; d++)
        aq[d] = *(const bf16x8*)(qb + (size_t)qrow * DM + head * DH + d * 32 + quad * 8);

    size_t koff[4], voff[4];
#pragma unroll
    for (int j = 0; j < 4; j++) {
        int ck = (wave * 4 + j) * 64 + lane;
        int krow = ck >> 4, ku = (ck & 15) ^ (krow & 7);
        koff[j] = (size_t)krow * DM + head * DH + ku * 8;
        int cv = (wave * 4 + j) * 64 + lane;
        int vrow = cv >> 3, vu = (cv & 7) ^ (vrow & 7);
        voff[j] = (size_t)(head * DH + vrow) * LSEQ + vu * 8;
    }

    f32x4 o[8];
#pragma unroll
    for (int i = 0; i < 8; i++) o[i] = f32x4{0.f, 0.f, 0.f, 0.f};
    float m_i = -INFINITY, l_i = 0.f;
    __bf16* pw = sP + wave * (16 * 64);

    for (int kv0 = 0; kv0 < LSEQ; kv0 += 64) {
        __syncthreads();
#pragma unroll
        for (int j = 0; j < 4; j++)
            async_copy16(kb + koff[j] + (size_t)kv0 * DM, (char*)sK + (wave * 4 + j) * 1024);
#pragma unroll
        for (int j = 0; j < 4; j++)
            async_copy16(vt + voff[j] + kv0, (char*)sV + (wave * 4 + j) * 1024);
        __syncthreads();

        f32x4 st[4];
        __builtin_amdgcn_s_setprio(1);
#pragma unroll
        for (int b = 0; b < 4; b++) {
            st[b] = f32x4{0.f, 0.f, 0.f, 0.f};
#pragma unroll
            for (int d = 0; d < 4; d++) {
                int row = b * 16 + l15;
                bf16x8 ak = *(const bf16x8*)(sK + row * 128 + (((d * 4 + quad) ^ (row & 7)) * 8));
                st[b] = __builtin_amdgcn_mfma_f32_16x16x32_bf16(ak, aq[d], st[b], 0, 0, 0);
            }
        }
        __builtin_amdgcn_s_setprio(0);

        float mx = m_i;
#pragma unroll
        for (int b = 0; b < 4; b++)
#pragma unroll
            for (int r = 0; r < 4; r++) { st[b][r] *= SCALE; mx = fmaxf(mx, st[b][r]); }
        mx = fmaxf(mx, __shfl_xor(mx, 16));
        mx = fmaxf(mx, __shfl_xor(mx, 32));
        const float al = __expf(m_i - mx);
        m_i = mx;
        float sum = 0.f;
#pragma unroll
        for (int b = 0; b < 4; b++)
#pragma unroll
            for (int r = 0; r < 4; r++) {
                float p = __expf(st[b][r] - mx);
                st[b][r] = p;
                sum += p;
            }
        sum += __shfl_xor(sum, 16);
        sum += __shfl_xor(sum, 32);
        l_i = l_i * al + sum;

#pragma unroll
        for (int b = 0; b < 4; b++) {
            bf16x4 pk = {(__bf16)st[b][0], (__bf16)st[b][1], (__bf16)st[b][2], (__bf16)st[b][3]};
            int u = 2 * b + (quad >> 1);
            *(bf16x4*)(pw + l15 * 64 + ((u ^ (l15 & 7)) * 8) + (quad & 1) * 4) = pk;
        }

        float alr[4];
#pragma unroll
        for (int r = 0; r < 4; r++) alr[r] = __shfl(al, quad * 4 + r);
#pragma unroll
        for (int i = 0; i < 8; i++) {
            f32x4 tmp = o[i];
            tmp[0] *= alr[0]; tmp[1] *= alr[1]; tmp[2] *= alr[2]; tmp[3] *= alr[3];
            o[i] = tmp;
        }
        __asm__ volatile("s_waitcnt lgkmcnt(0)" ::: "memory");

        bf16x8 ap0 = *(const bf16x8*)(pw + l15 * 64 + ((quad ^ (l15 & 7)) * 8));
        bf16x8 ap1 = *(const bf16x8*)(pw + l15 * 64 + (((4 + quad) ^ (l15 & 7)) * 8));
        __builtin_amdgcn_s_setprio(1);
#pragma unroll
        for (int n2 = 0; n2 < 8; n2++) {
            int row = n2 * 16 + l15;
            bf16x8 bv0 = *(const bf16x8*)(sV + row * 64 + ((quad ^ (row & 7)) * 8));
            bf16x8 bv1 = *(const bf16x8*)(sV + row * 64 + (((4 + quad) ^ (row & 7)) * 8));
            o[n2] = __builtin_amdgcn_mfma_f32_16x16x32_bf16(ap0, bv0, o[n2], 0, 0, 0);
            o[n2] = __builtin_amdgcn_mfma_f32_16x16x32_bf16(ap1, bv1, o[n2], 0, 0, 0);
        }
        __builtin_amdgcn_s_setprio(0);
    }

    const float inv = 1.0f / l_i;
    float invr[4];
#pragma unroll
    for (int r = 0; r < 4; r++) invr[r] = __shfl(inv, quad * 4 + r);
#pragma unroll
    for (int n2 = 0; n2 < 8; n2++)
#pragma unroll
        for (int r = 0; r < 4; r++)
            ob[(size_t)(q0 + wave * 16 + quad * 4 + r) * DM + head * DH + n2 * 16 + l15] =
                (__bf16)(o[n2][r] * invr[r]);
}

// ---------------- launch ----------------

extern "C" void kernel_launch(void* const* d_in, const int* in_sizes, int n_in,
                              void* d_out, int out_size, void* d_ws, size_t ws_size,
                              hipStream_t stream) {
    const float* img       = (const float*)d_in[0];
    const float* txt       = (const float*)d_in[1];
    const float* rope      = (const float*)d_in[2];
    const float* img_masks = (const float*)d_in[3];
    const float* Wq   = (const float*)d_in[4];  const float* bq   = (const float*)d_in[5];
    const float* Wk   = (const float*)d_in[6];  const float* bk   = (const float*)d_in[7];
    const float* Wv   = (const float*)d_in[8];  const float* bv   = (const float*)d_in[9];
    const float* Wo   = (const float*)d_in[10]; const float* bo   = (const float*)d_in[11];
    const float* Wq_t = (const float*)d_in[12]; const float* bq_t = (const float*)d_in[13];
    const float* Wk_t = (const float*)d_in[14]; const float* bk_t = (const float*)d_in[15];
    const float* Wv_t = (const float*)d_in[16]; const float* bv_t = (const float*)d_in[17];
    const float* Wo_t = (const float*)d_in[18]; const float* bo_t = (const float*)d_in[19];
    const float* qn   = (const float*)d_in[20]; const float* kn   = (const float*)d_in[21];
    const float* qn_t = (const float*)d_in[22]; const float* kn_t = (const float*)d_in[23];
    float* out = (float*)d_out;

    static bool inited = false;
    if (!inited) {
        hipFuncSetAttribute(reinterpret_cast<const void*>(gemm8_qkv_kernel),
                            hipFuncAttributeMaxDynamicSharedMemorySize, 131072);
        inited = true;
    }

    const size_t WELEM = (size_t)DM * DM;
    const size_t XELEM = (size_t)LSEQ * DM;

    __bf16* wbf  = (__bf16*)d_ws;
    __bf16* xbf  = wbf + 8 * WELEM;
    float*  qraw = (float*)(xbf + XELEM);
    float*  kraw = qraw + XELEM;
    float*  vraw = kraw + XELEM;
    __bf16* qbf  = (__bf16*)(vraw + XELEM);
    __bf16* kbf  = qbf + XELEM;
    __bf16* vt   = kbf + XELEM;
    __bf16* attnbf = (__bf16*)qraw;                // reuse (qraw dead after rmsrope)

    cvt8_kernel<<<dim3((int)(WELEM / 8 / 256), 8), 256, 0, stream>>>(
        Wq, Wk, Wv, Wo, Wq_t, Wk_t, Wv_t, Wo_t, wbf);
    cvt_kernel<<<dim3((LI * DM / 8 + 255) / 256), 256, 0, stream>>>(img, xbf, LI * DM / 8);
    cvt_kernel<<<dim3((LT * DM / 8 + 255) / 256), 256, 0, stream>>>(
        txt, xbf + (size_t)LI * DM, LT * DM / 8);

    gemm8_qkv_kernel<<<dim3(30, 10), 512, 131072, stream>>>(
        xbf, wbf, bq, bk, bv, bq_t, bk_t, bv_t, qraw, kraw, vraw);

    rmsrope_kernel<<<dim3(LSEQ), 256, 0, stream>>>(
        qraw, kraw, rope, img_masks, qn, kn, qn_t, kn_t, qbf, kbf);

    transpose_cvt_kernel<<<dim3(DM / 32, LSEQ / 32), 256, 0, stream>>>(vraw, vt);

    flash_kernel<<<dim3(NH, LSEQ / 64), 256, 0, stream>>>(qbf, kbf, vt, attnbf);

    gemm_out_kernel<<<dim3(20, 19), 256, 0, stream>>>(attnbf, wbf, bo, bo_t, out);
}

// Round 2
// 584.370 us; speedup vs baseline: 1.0388x; 1.0388x over previous
//
#include <hip/hip_runtime.h>
#include <math.h>

#define LI 2048
#define LT 384
#define LSEQ 2432
#define DM 2560
#define NH 20
#define DH 128
#define SCALE 0.08838834764831845f

typedef __bf16 bf16x8 __attribute__((ext_vector_type(8)));
typedef __bf16 bf16x4 __attribute__((ext_vector_type(4)));
typedef __bf16 bf16x2 __attribute__((ext_vector_type(2)));
typedef float f32x4 __attribute__((ext_vector_type(4)));

__device__ __forceinline__ void async_copy16(const void* gsrc, void* lds_uniform) {
    __builtin_amdgcn_global_load_lds(
        (const __attribute__((address_space(1))) unsigned int*)gsrc,
        (__attribute__((address_space(3))) unsigned int*)lds_uniform,
        16, 0, 0);
}

// ---------------- f32 -> bf16 conversions ----------------

__global__ __launch_bounds__(256) void cvt8_kernel(
    const float* __restrict__ s0, const float* __restrict__ s1,
    const float* __restrict__ s2, const float* __restrict__ s3,
    const float* __restrict__ s4, const float* __restrict__ s5,
    const float* __restrict__ s6, const float* __restrict__ s7,
    __bf16* __restrict__ dst)
{
    const float* srcs[8] = {s0, s1, s2, s3, s4, s5, s6, s7};
    const float* s = srcs[blockIdx.y];
    __bf16* d = dst + (size_t)blockIdx.y * (size_t)DM * DM;
    int i = blockIdx.x * 256 + threadIdx.x;
    const float4* sp = (const float4*)s + (size_t)i * 2;
    float4 a = sp[0], b = sp[1];
    bf16x8 o = {(__bf16)a.x, (__bf16)a.y, (__bf16)a.z, (__bf16)a.w,
                (__bf16)b.x, (__bf16)b.y, (__bf16)b.z, (__bf16)b.w};
    *((bf16x8*)d + i) = o;
}

__global__ __launch_bounds__(256) void cvt_kernel(
    const float* __restrict__ s, __bf16* __restrict__ d, int n8)
{
    int i = blockIdx.x * 256 + threadIdx.x;
    if (i >= n8) return;
    const float4* sp = (const float4*)s + (size_t)i * 2;
    float4 a = sp[0], b = sp[1];
    bf16x8 o = {(__bf16)a.x, (__bf16)a.y, (__bf16)a.z, (__bf16)a.w,
                (__bf16)b.x, (__bf16)b.y, (__bf16)b.z, (__bf16)b.w};
    *((bf16x8*)d + i) = o;
}

// ---------------- 128x128 bf16 GEMM core, BK=64, XOR-swizzled LDS ----------------
// C = A @ B^T + bias (f32 out). A: (M,2560), B: (N,2560) bf16 row-major.
// LDS tiles 128x64, 8 16B-units per row; physical unit = logical ^ (row&7).

__device__ __forceinline__ void gemm_core(
    const __bf16* __restrict__ Ab,    // A + m0*2560
    const __bf16* __restrict__ Bb,    // B + n_local*2560
    const float* __restrict__ bias,   // + n_local
    float* __restrict__ Cb,           // C + m0*2560 + n_local (ld = 2560)
    __bf16* sA, __bf16* sB)
{
    const int t = threadIdx.x, wave = t >> 6, lane = t & 63;
    const int l15 = lane & 15, quad = lane >> 4;
    const int wm = wave >> 1, wn = wave & 1;

    f32x4 acc[4][4];
#pragma unroll
    for (int i = 0; i < 4; i++)
#pragma unroll
        for (int j = 0; j < 4; j++) acc[i][j] = f32x4{0.f, 0.f, 0.f, 0.f};

    // staging source offsets (swizzle inverted): unit c = j*256 + t
    size_t soff[4];
#pragma unroll
    for (int j = 0; j < 4; j++) {
        int c = j * 256 + t;
        int row = c >> 3, u = c & 7;
        soff[j] = (size_t)row * DM + ((u ^ (row & 7)) * 8);
    }

    for (int k0 = 0; k0 < DM; k0 += 64) {
        __syncthreads();
#pragma unroll
        for (int j = 0; j < 4; j++)
            async_copy16(Ab + soff[j] + k0, (char*)sA + (j * 256 + wave * 64) * 16);
#pragma unroll
        for (int j = 0; j < 4; j++)
            async_copy16(Bb + soff[j] + k0, (char*)sB + (j * 256 + wave * 64) * 16);
        __syncthreads();

#pragma unroll
        for (int ks = 0; ks < 2; ks++) {
            bf16x8 af[4], bg[4];
#pragma unroll
            for (int mt = 0; mt < 4; mt++) {
                int r = wm * 64 + mt * 16 + l15;
                af[mt] = *(const bf16x8*)(sA + r * 64 + (((quad + ks * 4) ^ (r & 7)) * 8));
            }
#pragma unroll
            for (int nt = 0; nt < 4; nt++) {
                int r = wn * 64 + nt * 16 + l15;
                bg[nt] = *(const bf16x8*)(sB + r * 64 + (((quad + ks * 4) ^ (r & 7)) * 8));
            }
#pragma unroll
            for (int mt = 0; mt < 4; mt++)
#pragma unroll
                for (int nt = 0; nt < 4; nt++)
                    acc[mt][nt] = __builtin_amdgcn_mfma_f32_16x16x32_bf16(af[mt], bg[nt], acc[mt][nt], 0, 0, 0);
        }
    }

#pragma unroll
    for (int mt = 0; mt < 4; mt++) {
        const int row = wm * 64 + mt * 16 + quad * 4;
#pragma unroll
        for (int nt = 0; nt < 4; nt++) {
            const int col = wn * 64 + nt * 16 + l15;
            const float bv = bias[col];
            float* cp = Cb + (size_t)row * DM + col;
            cp[0]        = acc[mt][nt][0] + bv;
            cp[DM]       = acc[mt][nt][1] + bv;
            cp[2 * DM]   = acc[mt][nt][2] + bv;
            cp[3 * DM]   = acc[mt][nt][3] + bv;
        }
    }
}

// QKV: grid (60, 19). XCD-chunked bijective remap (T1): linear dispatch id ->
// per-XCD contiguous L-range over (panel, atile) pairs ordered atile-fastest,
// so each XCD's L2 holds ~7.5 weight panels (~4.9 MB) reused 19x each.
// 1140 = 4*143 + 4*142 (bijective).
__global__ __launch_bounds__(256, 4) void gemm_qkv_kernel(
    const __bf16* __restrict__ xbf, const __bf16* __restrict__ wbf,
    const float* __restrict__ bq, const float* __restrict__ bk, const float* __restrict__ bv,
    const float* __restrict__ bq_t, const float* __restrict__ bk_t, const float* __restrict__ bv_t,
    float* __restrict__ qraw, float* __restrict__ kraw, float* __restrict__ vraw)
{
    __shared__ alignas(16) __bf16 sA[128 * 64];
    __shared__ alignas(16) __bf16 sB[128 * 64];
    const int virt = blockIdx.y * 60 + blockIdx.x;
    const int xcd = virt & 7, s = virt >> 3;
    const int L = (xcd < 4 ? xcd * 143 : 572 + (xcd - 4) * 142) + s;
    const int nblk = L / 19;                   // 0..59 weight panel
    const int mblk = L % 19;                   // 0..18 A tile
    const int which = nblk / 20;               // 0=Q 1=K 2=V
    const int nloc = (nblk % 20) * 128;
    const bool is_txt = (mblk >= 16);
    const size_t WELEM = (size_t)DM * DM;
    const int widx = which + (is_txt ? 4 : 0);
    const __bf16* W = wbf + (size_t)widx * WELEM;
    const float* bias = (which == 0) ? (is_txt ? bq_t : bq)
                      : (which == 1) ? (is_txt ? bk_t : bk)
                                     : (is_txt ? bv_t : bv);
    float* C = (which == 0) ? qraw : (which == 1) ? kraw : vraw;
    gemm_core(xbf + (size_t)mblk * 128 * DM, W + (size_t)nloc * DM, bias + nloc,
              C + (size_t)mblk * 128 * DM + nloc, sA, sB);
}

// Out-proj: grid (20, 19). Same XCD-chunked remap; 380 = 4*48 + 4*47.
__global__ __launch_bounds__(256, 4) void gemm_out_kernel(
    const __bf16* __restrict__ attnbf, const __bf16* __restrict__ wbf,
    const float* __restrict__ bo, const float* __restrict__ bo_t,
    float* __restrict__ out)
{
    __shared__ alignas(16) __bf16 sA[128 * 64];
    __shared__ alignas(16) __bf16 sB[128 * 64];
    const int virt = blockIdx.y * 20 + blockIdx.x;
    const int xcd = virt & 7, s = virt >> 3;
    const int L = (xcd < 4 ? xcd * 48 : 192 + (xcd - 4) * 47) + s;
    const int nblk = L / 19;                   // 0..19 weight panel
    const int mblk = L % 19;                   // 0..18 A tile
    const bool is_txt = (mblk >= 16);
    const size_t WELEM = (size_t)DM * DM;
    const __bf16* W = wbf + (size_t)(is_txt ? 7 : 3) * WELEM;
    const float* bias = (is_txt ? bo_t : bo) + nblk * 128;
    gemm_core(attnbf + (size_t)mblk * 128 * DM, W + (size_t)nblk * 128 * DM, bias,
              out + (size_t)mblk * 128 * DM + nblk * 128, sA, sB);
}

// ---------------- RMS norm + qn/kn + mask + RoPE, f32 -> bf16 ----------------

__global__ __launch_bounds__(256) void rmsrope_kernel(
    const float* __restrict__ qraw, const float* __restrict__ kraw,
    const float* __restrict__ rope, const float* __restrict__ img_masks,
    const float* __restrict__ qn, const float* __restrict__ kn,
    const float* __restrict__ qn_t, const float* __restrict__ kn_t,
    __bf16* __restrict__ qbf, __bf16* __restrict__ kbf)
{
    const int l = blockIdx.x, t = threadIdx.x;
    const int wave = t >> 6, lane = t & 63;
    const bool is_img = (l < LI);
    const float* qw = is_img ? qn : qn_t;
    const float* kw = is_img ? kn : kn_t;
    const float kmask = is_img ? img_masks[l] : 1.0f;
    const float* qr = qraw + (size_t)l * DM;
    const float* kr = kraw + (size_t)l * DM;

    float2 qv[5], kv[5];
    float sq = 0.f, sk = 0.f;
#pragma unroll
    for (int j = 0; j < 5; j++) {
        int c2 = j * 256 + t;
        qv[j] = *(const float2*)(qr + 2 * c2);
        kv[j] = *(const float2*)(kr + 2 * c2);
        sq += qv[j].x * qv[j].x + qv[j].y * qv[j].y;
        sk += kv[j].x * kv[j].x + kv[j].y * kv[j].y;
    }
#pragma unroll
    for (int m = 32; m; m >>= 1) { sq += __shfl_xor(sq, m); sk += __shfl_xor(sk, m); }
    __shared__ float redq[4], redk[4];
    if (lane == 0) { redq[wave] = sq; redk[wave] = sk; }
    __syncthreads();
    sq = redq[0] + redq[1] + redq[2] + redq[3];
    sk = redk[0] + redk[1] + redk[2] + redk[3];
    const float rq = rsqrtf(sq * (1.0f / DM) + 1e-5f);
    const float rk = rsqrtf(sk * (1.0f / DM) + 1e-5f) * kmask;

#pragma unroll
    for (int j = 0; j < 5; j++) {
        int c2 = j * 256 + t;
        int c = 2 * c2;
        float4 rp = *(const float4*)(rope + ((size_t)l * 64 + (c2 & 63)) * 4);
        float2 w2q = *(const float2*)(qw + c);
        float2 w2k = *(const float2*)(kw + c);
        float x0 = qv[j].x * rq * w2q.x, x1 = qv[j].y * rq * w2q.y;
        bf16x2 oq = {(__bf16)(rp.x * x0 + rp.y * x1), (__bf16)(rp.z * x0 + rp.w * x1)};
        *(bf16x2*)(qbf + (size_t)l * DM + c) = oq;
        float y0 = kv[j].x * rk * w2k.x, y1 = kv[j].y * rk * w2k.y;
        bf16x2 ok = {(__bf16)(rp.x * y0 + rp.y * y1), (__bf16)(rp.z * y0 + rp.w * y1)};
        *(bf16x2*)(kbf + (size_t)l * DM + c) = ok;
    }
}

// ---------------- transpose V (L,DM) f32 -> (DM,L) bf16 ----------------

__global__ __launch_bounds__(256) void transpose_cvt_kernel(
    const float* __restrict__ src, __bf16* __restrict__ dst)
{
    __shared__ float tile[32][33];
    const int c0 = blockIdx.x * 32;
    const int r0 = blockIdx.y * 32;
    const int tc = threadIdx.x & 31, tr = threadIdx.x >> 5;
#pragma unroll
    for (int j = 0; j < 4; j++)
        tile[tr + j * 8][tc] = src[(size_t)(r0 + tr + j * 8) * DM + c0 + tc];
    __syncthreads();
#pragma unroll
    for (int j = 0; j < 4; j++)
        dst[(size_t)(c0 + tr + j * 8) * LSEQ + r0 + tc] = (__bf16)tile[tc][tr + j * 8];
}

// ---------------- flash attention ----------------

__global__ __launch_bounds__(256, 4) void flash_kernel(
    const __bf16* __restrict__ qb, const __bf16* __restrict__ kb,
    const __bf16* __restrict__ vt, __bf16* __restrict__ ob)
{
    __shared__ alignas(16) __bf16 sK[64 * DH];      // [kv 64][d 128]
    __shared__ alignas(16) __bf16 sV[DH * 64];      // [d 128][kv 64]
    __shared__ alignas(16) __bf16 sP[4 * 16 * 64];  // per-wave [q 16][kv 64]
    const int head = blockIdx.x;
    const int q0 = blockIdx.y * 64;
    const int t = threadIdx.x, wave = t >> 6, lane = t & 63;
    const int l15 = lane & 15, quad = lane >> 4;
    const int qrow = q0 + wave * 16 + l15;

    bf16x8 aq[4];
#pragma unroll
    for (int d = 0; d < 4; d++)
        aq[d] = *(const bf16x8*)(qb + (size_t)qrow * DM + head * DH + d * 32 + quad * 8);

    size_t koff[4], voff[4];
#pragma unroll
    for (int j = 0; j < 4; j++) {
        int ck = (wave * 4 + j) * 64 + lane;
        int krow = ck >> 4, ku = (ck & 15) ^ (krow & 7);
        koff[j] = (size_t)krow * DM + head * DH + ku * 8;
        int cv = (wave * 4 + j) * 64 + lane;
        int vrow = cv >> 3, vu = (cv & 7) ^ (vrow & 7);
        voff[j] = (size_t)(head * DH + vrow) * LSEQ + vu * 8;
    }

    f32x4 o[8];
#pragma unroll
    for (int i = 0; i < 8; i++) o[i] = f32x4{0.f, 0.f, 0.f, 0.f};
    float m_i = -INFINITY, l_i = 0.f;
    __bf16* pw = sP + wave * (16 * 64);

    for (int kv0 = 0; kv0 < LSEQ; kv0 += 64) {
        __syncthreads();
#pragma unroll
        for (int j = 0; j < 4; j++)
            async_copy16(kb + koff[j] + (size_t)kv0 * DM, (char*)sK + (wave * 4 + j) * 1024);
#pragma unroll
        for (int j = 0; j < 4; j++)
            async_copy16(vt + voff[j] + kv0, (char*)sV + (wave * 4 + j) * 1024);
        __syncthreads();

        f32x4 st[4];
        __builtin_amdgcn_s_setprio(1);
#pragma unroll
        for (int b = 0; b < 4; b++) {
            st[b] = f32x4{0.f, 0.f, 0.f, 0.f};
#pragma unroll
            for (int d = 0; d < 4; d++) {
                int row = b * 16 + l15;
                bf16x8 ak = *(const bf16x8*)(sK + row * 128 + (((d * 4 + quad) ^ (row & 7)) * 8));
                st[b] = __builtin_amdgcn_mfma_f32_16x16x32_bf16(ak, aq[d], st[b], 0, 0, 0);
            }
        }
        __builtin_amdgcn_s_setprio(0);

        float mx = m_i;
#pragma unroll
        for (int b = 0; b < 4; b++)
#pragma unroll
            for (int r = 0; r < 4; r++) { st[b][r] *= SCALE; mx = fmaxf(mx, st[b][r]); }
        mx = fmaxf(mx, __shfl_xor(mx, 16));
        mx = fmaxf(mx, __shfl_xor(mx, 32));
        const float al = __expf(m_i - mx);
        m_i = mx;
        float sum = 0.f;
#pragma unroll
        for (int b = 0; b < 4; b++)
#pragma unroll
            for (int r = 0; r < 4; r++) {
                float p = __expf(st[b][r] - mx);
                st[b][r] = p;
                sum += p;
            }
        sum += __shfl_xor(sum, 16);
        sum += __shfl_xor(sum, 32);
        l_i = l_i * al + sum;

#pragma unroll
        for (int b = 0; b < 4; b++) {
            bf16x4 pk = {(__bf16)st[b][0], (__bf16)st[b][1], (__bf16)st[b][2], (__bf16)st[b][3]};
            int u = 2 * b + (quad >> 1);
            *(bf16x4*)(pw + l15 * 64 + ((u ^ (l15 & 7)) * 8) + (quad & 1) * 4) = pk;
        }

        float alr[4];
#pragma unroll
        for (int r = 0; r < 4; r++) alr[r] = __shfl(al, quad * 4 + r);
#pragma unroll
        for (int i = 0; i < 8; i++) {
            f32x4 tmp = o[i];
            tmp[0] *= alr[0]; tmp[1] *= alr[1]; tmp[2] *= alr[2]; tmp[3] *= alr[3];
            o[i] = tmp;
        }
        __asm__ volatile("s_waitcnt lgkmcnt(0)" ::: "memory");

        bf16x8 ap0 = *(const bf16x8*)(pw + l15 * 64 + ((quad ^ (l15 & 7)) * 8));
        bf16x8 ap1 = *(const bf16x8*)(pw + l15 * 64 + (((4 + quad) ^ (l15 & 7)) * 8));
        __builtin_amdgcn_s_setprio(1);
#pragma unroll
        for (int n2 = 0; n2 < 8; n2++) {
            int row = n2 * 16 + l15;
            bf16x8 bv0 = *(const bf16x8*)(sV + row * 64 + ((quad ^ (row & 7)) * 8));
            bf16x8 bv1 = *(const bf16x8*)(sV + row * 64 + (((4 + quad) ^ (row & 7)) * 8));
            o[n2] = __builtin_amdgcn_mfma_f32_16x16x32_bf16(ap0, bv0, o[n2], 0, 0, 0);
            o[n2] = __builtin_amdgcn_mfma_f32_16x16x32_bf16(ap1, bv1, o[n2], 0, 0, 0);
        }
        __builtin_amdgcn_s_setprio(0);
    }

    const float inv = 1.0f / l_i;
    float invr[4];
#pragma unroll
    for (int r = 0; r < 4; r++) invr[r] = __shfl(inv, quad * 4 + r);
#pragma unroll
    for (int n2 = 0; n2 < 8; n2++)
#pragma unroll
        for (int r = 0; r < 4; r++)
            ob[(size_t)(q0 + wave * 16 + quad * 4 + r) * DM + head * DH + n2 * 16 + l15] =
                (__bf16)(o[n2][r] * invr[r]);
}

// ---------------- launch ----------------

extern "C" void kernel_launch(void* const* d_in, const int* in_sizes, int n_in,
                              void* d_out, int out_size, void* d_ws, size_t ws_size,
                              hipStream_t stream) {
    const float* img       = (const float*)d_in[0];
    const float* txt       = (const float*)d_in[1];
    const float* rope      = (const float*)d_in[2];
    const float* img_masks = (const float*)d_in[3];
    const float* Wq   = (const float*)d_in[4];  const float* bq   = (const float*)d_in[5];
    const float* Wk   = (const float*)d_in[6];  const float* bk   = (const float*)d_in[7];
    const float* Wv   = (const float*)d_in[8];  const float* bv   = (const float*)d_in[9];
    const float* Wo   = (const float*)d_in[10]; const float* bo   = (const float*)d_in[11];
    const float* Wq_t = (const float*)d_in[12]; const float* bq_t = (const float*)d_in[13];
    const float* Wk_t = (const float*)d_in[14]; const float* bk_t = (const float*)d_in[15];
    const float* Wv_t = (const float*)d_in[16]; const float* bv_t = (const float*)d_in[17];
    const float* Wo_t = (const float*)d_in[18]; const float* bo_t = (const float*)d_in[19];
    const float* qn   = (const float*)d_in[20]; const float* kn   = (const float*)d_in[21];
    const float* qn_t = (const float*)d_in[22]; const float* kn_t = (const float*)d_in[23];
    float* out = (float*)d_out;

    const size_t WELEM = (size_t)DM * DM;
    const size_t XELEM = (size_t)LSEQ * DM;

    __bf16* wbf  = (__bf16*)d_ws;
    __bf16* xbf  = wbf + 8 * WELEM;
    float*  qraw = (float*)(xbf + XELEM);
    float*  kraw = qraw + XELEM;
    float*  vraw = kraw + XELEM;
    __bf16* qbf  = (__bf16*)(vraw + XELEM);
    __bf16* kbf  = qbf + XELEM;
    __bf16* vt   = kbf + XELEM;
    __bf16* attnbf = (__bf16*)qraw;                // reuse (qraw dead after rmsrope)

    cvt8_kernel<<<dim3((int)(WELEM / 8 / 256), 8), 256, 0, stream>>>(
        Wq, Wk, Wv, Wo, Wq_t, Wk_t, Wv_t, Wo_t, wbf);
    cvt_kernel<<<dim3((LI * DM / 8 + 255) / 256), 256, 0, stream>>>(img, xbf, LI * DM / 8);
    cvt_kernel<<<dim3((LT * DM / 8 + 255) / 256), 256, 0, stream>>>(
        txt, xbf + (size_t)LI * DM, LT * DM / 8);

    gemm_qkv_kernel<<<dim3(60, 19), 256, 0, stream>>>(
        xbf, wbf, bq, bk, bv, bq_t, bk_t, bv_t, qraw, kraw, vraw);

    rmsrope_kernel<<<dim3(LSEQ), 256, 0, stream>>>(
        qraw, kraw, rope, img_masks, qn, kn, qn_t, kn_t, qbf, kbf);

    transpose_cvt_kernel<<<dim3(DM / 32, LSEQ / 32), 256, 0, stream>>>(vraw, vt);

    flash_kernel<<<dim3(NH, LSEQ / 64), 256, 0, stream>>>(qbf, kbf, vt, attnbf);

    gemm_out_kernel<<<dim3(20, 19), 256, 0, stream>>>(attnbf, wbf, bo, bo_t, out);
}